// Round 15
// baseline (145.899 us; speedup 1.0000x reference)
//
#include <hip/hip_runtime.h>
#include <cstdint>
#include <cstddef>

// Problem: B=8, C=64, H=W=32 -> N=8192 nodes, K=9 neighbors, OUT=64.
// Batches: b = [1024b,1024(b+1)) for b<=6, batch 7 = [7168,8190], batch 8 = {8191}.
// Node g <-> (b = g>>10, hw = g&1023); features x[b][c][hw] (node 8191 -> b=7).
//
// R21: CODE-SIZE compaction. Five structures (R13/16/17/18/20) all 54-68us,
//  VALUBusy 33-40%, pipes underloaded, cost smeared across phases (R19) ->
//  shared invariant = ~50-80KB unrolled selection code vs 32KB I$ (4x row
//  replication x 9 unrolled rounds x unrolled rescans). Fix: selection body
//  exists ONCE (runtime-rr '#pragma unroll 1' loop). Static-index constraint
//  (rule #20) bridged via LDS: tiny static-rr keygen (4 switch cases) writes
//  16 keys/thread to LDS scratch (32KB, overlays dead A-region; per-thread
//  private -> no barriers); shared body reloads to static kreg[16] and runs
//  the R20-proven top-2 + DPP tournament verbatim; rescan (rare) reads LDS
//  non-unrolled; transform c-loop non-unrolled (runtime readlane/LDS addr);
//  means bridge via ms_f LDS. All arithmetic chains unchanged -> bitwise-
//  identical output. Geometry unchanged: 512 blocks x 16 rows, 4 rows/wave,
//  B from global (L2-resident), LDS 37.4KB -> 2 blocks/CU.

typedef unsigned long long u64;

// 64-bit wave-min via DPP (VALU pipe, ~2-4cyc/level vs ds_bpermute ~40+):
// xor1, xor2, half_mirror(8), mirror(16), bcast15(->32), bcast31(->64);
// global min lands in lane 63. Idempotent-min full-mixing network (R20-proven).
#define DPPMIN(CTRL)                                                         \
  {                                                                          \
    unsigned oh_ = (unsigned)__builtin_amdgcn_update_dpp(                    \
        (int)gh, (int)gh, CTRL, 0xF, 0xF, false);                            \
    unsigned ol_ = (unsigned)__builtin_amdgcn_update_dpp(                    \
        (int)gl, (int)gl, CTRL, 0xF, 0xF, false);                            \
    u64 cur_ = ((u64)gh << 32) | gl;                                         \
    u64 oth_ = ((u64)oh_ << 32) | ol_;                                       \
    bool take_ = oth_ < cur_;                                                \
    gh = take_ ? oh_ : gh;                                                   \
    gl = take_ ? ol_ : gl;                                                   \
  }

// keygen for row RR (static): keys -> cand LDS. Key = (orderable-dist<<32)|jj,
// jj = 256q + 4*lane + e; slot = 4q+e. Poison slot15/lane63 for batch-7 rows.
#define KEYGEN(RR)                                                           \
  {                                                                          \
    int n_ = n0 + (w << 2) + RR;                                             \
    int ln_ = n_ - s;                                                        \
    int so_ = ((ln_ >> 8) << 2) | (ln_ & 3);                                 \
    float sv_ = sqa[0];                                                      \
    _Pragma("unroll")                                                        \
    for (int j_ = 1; j_ < 16; ++j_) sv_ = (so_ == j_) ? sqa[j_] : sv_;       \
    float si_ = __int_as_float(__builtin_amdgcn_readlane(                    \
        __float_as_int(sv_), (ln_ & 255) >> 2));                             \
    bool ml_ = (n_ >= 7168);                                                 \
    _Pragma("unroll")                                                        \
    for (int q_ = 0; q_ < 4; ++q_)                                           \
      _Pragma("unroll")                                                      \
      for (int e_ = 0; e_ < 4; ++e_) {                                       \
        int sl_ = (q_ << 2) + e_;                                            \
        float d_ = (si_ + sqa[sl_]) - 2.f * acc[RR][sl_];                    \
        unsigned u_ = __float_as_uint(d_);                                   \
        u_ = (u_ & 0x80000000u) ? ~u_ : (u_ | 0x80000000u);                  \
        u64 k_ = ((u64)u_ << 32) |                                           \
                 (unsigned)((q_ << 8) + (lane << 2) + e_);                   \
        if (sl_ == 15) k_ = (ml_ && lane == 63) ? ~0ull : k_;                \
        cand[(sl_ << 8) + t] = k_;                                           \
      }                                                                      \
  }

__global__ __launch_bounds__(256, 2) void k_all(const float* __restrict__ x,
                                                const float* __restrict__ Wl,
                                                const float* __restrict__ bl,
                                                const float* __restrict__ Wr,
                                                float* __restrict__ out) {
  // LDS arena (37,376 B):
  //  floats [0, 8320): phase1 = Asf (A frags, first 4KB); phase2 = cand
  //    (u64[16][256] = 32,768 B, per-thread private scratch); phase3 = W
  //    overlay (WsL [64][65] @0, WsR @4160).
  //  floats [8320, 9344): ms_f[4 rr][4 w][64 ch] scaled means.
  __shared__ float SH[9344];
  float* ms_f = SH + 8320;
  float4* Asf4 = (float4*)SH;
  u64* cand = (u64*)SH;

  int bi = (int)blockIdx.x, t = threadIdx.x;
  int lane = t & 63, w = t >> 6;
  int n0 = bi << 4;                  // 16 rows/block; batch bounds 16-aligned
  int s = (n0 >= 7168) ? 7168 : (n0 & ~1023);
  const float* xb = x + ((size_t)(s >> 10) << 16);       // batch plane base
  const float* xrow = x + ((size_t)(n0 >> 10) << 16) + (n0 & 1023);

  // stage A: ch = t>>2, grp g = t&3 -> rows n0+4g..n0+4g+3 of channel ch
  {
    int ch = t >> 2, g = t & 3;
    Asf4[t] = *(const float4*)&xrow[((size_t)ch << 10) + (g << 2)];
  }
  __syncthreads();

  // own-rows feature (ch=lane); registers survive all overlays
  float4 av = Asf4[(lane << 2) + w];

  float acc[4][16];                  // rows 4w..4w+3 x lane's 16 cols
  float sqa[16];                     // lane's 16 col sq (ascending-ch chain)
#pragma unroll
  for (int r = 0; r < 4; ++r)
#pragma unroll
    for (int j = 0; j < 16; ++j) acc[r][j] = 0.f;
#pragma unroll
  for (int j = 0; j < 16; ++j) sqa[j] = 0.f;

  const float* xl = xb + (lane << 2);
#pragma unroll 4
  for (int ch = 0; ch < 64; ++ch) {
    float4 a4 = Asf4[(ch << 2) + w];                     // broadcast b128
    const float* xc = xl + ((size_t)ch << 10);
    float4 b0 = *(const float4*)&xc[0];                  // cols 4*lane..+3
    float4 b1 = *(const float4*)&xc[256];                // 256+4*lane..
    float4 b2 = *(const float4*)&xc[512];
    float4 b3 = *(const float4*)&xc[768];
    float bv[16] = {b0.x, b0.y, b0.z, b0.w, b1.x, b1.y, b1.z, b1.w,
                    b2.x, b2.y, b2.z, b2.w, b3.x, b3.y, b3.z, b3.w};
    float ar[4] = {a4.x, a4.y, a4.z, a4.w};
#pragma unroll
    for (int j = 0; j < 16; ++j) {
      sqa[j] = fmaf(bv[j], bv[j], sqa[j]);
      acc[0][j] = fmaf(ar[0], bv[j], acc[0][j]);
      acc[1][j] = fmaf(ar[1], bv[j], acc[1][j]);
      acc[2][j] = fmaf(ar[2], bv[j], acc[2][j]);
      acc[3][j] = fmaf(ar[3], bv[j], acc[3][j]);
    }
  }
  __syncthreads();                   // all waves past Asf reads -> cand overlay

  // ---- selection: rows sequential through ONE compact body ----
#pragma unroll 1
  for (int rr = 0; rr < 4; ++rr) {
    int n = n0 + (w << 2) + rr;
    if (rr == 0) KEYGEN(0)
    else if (rr == 1) KEYGEN(1)
    else if (rr == 2) KEYGEN(2)
    else KEYGEN(3)
    float xself = (rr == 0) ? av.x : (rr == 1) ? av.y : (rr == 2) ? av.z : av.w;
    float msv;
    if (n == 8191) {                 // singleton batch: mean = self
      msv = xself;
    } else {
      u64 kreg[16];                  // static-indexed reload (registers)
#pragma unroll
      for (int q = 0; q < 16; ++q) kreg[q] = cand[(q << 8) + t];
      // per-lane top-2 cache
      u64 m1 = kreg[0], m2 = kreg[1];
      if (m2 < m1) { u64 tt = m1; m1 = m2; m2 = tt; }
#pragma unroll
      for (int q = 2; q < 16; ++q) {
        u64 c = kreg[q];
        u64 lo = (c < m1) ? c : m1;
        u64 hi = (c < m1) ? m1 : c;
        m2 = (hi < m2) ? hi : m2;
        m1 = lo;
      }
      u64 lm = m1;
      unsigned rmask = 0;
      bool stale = false;
      unsigned jloc[9];
#pragma unroll
      for (int kk = 0; kk < 9; ++kk) {
        unsigned gh = (unsigned)(lm >> 32), gl = (unsigned)lm;
        DPPMIN(0xB1)                 // quad_perm xor1
        DPPMIN(0x4E)                 // quad_perm xor2
        DPPMIN(0x141)                // row_half_mirror : min-of-8
        DPPMIN(0x140)                // row_mirror      : min-of-16
        DPPMIN(0x142)                // row_bcast15     : min-of-32
        DPPMIN(0x143)                // row_bcast31     : min-of-64 @ lane63
        unsigned wh = __builtin_amdgcn_readlane((int)gh, 63);
        unsigned wl = __builtin_amdgcn_readlane((int)gl, 63);
        u64 g = ((u64)wh << 32) | wl;
        jloc[kk] = (unsigned)g & 1023u;
        if (lm == g) {               // exactly one winner lane (unique keys)
          unsigned slot = (((unsigned)g >> 6) & 12u) | ((unsigned)g & 3u);
          rmask |= 1u << slot;
          if (!stale) { lm = m2; stale = true; }
          else {                     // rare: compact rescan from LDS
            u64 best = ~0ull;
#pragma unroll 1
            for (int q = 0; q < 16; ++q) {
              u64 c = cand[(q << 8) + t];
              bool alive = ((rmask >> q) & 1u) == 0u;
              best = (alive && c < best) ? c : best;
            }
            lm = best;
          }
        }
      }
      // 9 independent gathers (wave-uniform jj; lane = channel), tree sum
      const float* gx = xb + ((size_t)lane << 10);
      float g0 = gx[jloc[0]], g1 = gx[jloc[1]], g2 = gx[jloc[2]];
      float g3 = gx[jloc[3]], g4 = gx[jloc[4]], g5 = gx[jloc[5]];
      float g6 = gx[jloc[6]], g7 = gx[jloc[7]], g8 = gx[jloc[8]];
      float msum = (((g0 + g1) + (g2 + g3)) + ((g4 + g5) + (g6 + g7))) + g8;
      msv = msum * (1.f / 9.f);
    }
    ms_f[(rr << 8) + t] = msv;       // [rr][w][lane]; runtime rr (LDS ok)
  }
  __syncthreads();                   // cand dead before W overlay

  // stage Ws over arena: WsL [64][65] @0, WsR @4160
#pragma unroll
  for (int i = 0; i < 16; ++i) {
    int lin = t + (i << 8);
    int o = lin >> 6, c = lin & 63;
    SH[o * 65 + c] = Wl[lin];
    SH[4160 + o * 65 + c] = Wr[lin];
  }
  __syncthreads();

  // transform: lane = output channel; mean-then-linear (= reference order).
  // Compact loop (runtime c): LDS broadcast means + SGPR readlane xself.
  float bias = bl[lane];
  float accL[4] = {0.f, 0.f, 0.f, 0.f};
  float accR[4] = {0.f, 0.f, 0.f, 0.f};
  int mbase = w << 6;
#pragma unroll 1
  for (int c = 0; c < 64; ++c) {
    float wlc = SH[lane * 65 + c];
    float wrc = SH[4160 + lane * 65 + c];
    float m0 = ms_f[mbase + c];
    float m1f = ms_f[256 + mbase + c];
    float m2f = ms_f[512 + mbase + c];
    float m3f = ms_f[768 + mbase + c];
    float x0 = __int_as_float(__builtin_amdgcn_readlane(__float_as_int(av.x), c));
    float x1 = __int_as_float(__builtin_amdgcn_readlane(__float_as_int(av.y), c));
    float x2 = __int_as_float(__builtin_amdgcn_readlane(__float_as_int(av.z), c));
    float x3 = __int_as_float(__builtin_amdgcn_readlane(__float_as_int(av.w), c));
    accL[0] = fmaf(m0, wlc, accL[0]);
    accL[1] = fmaf(m1f, wlc, accL[1]);
    accL[2] = fmaf(m2f, wlc, accL[2]);
    accL[3] = fmaf(m3f, wlc, accL[3]);
    accR[0] = fmaf(x0, wrc, accR[0]);
    accR[1] = fmaf(x1, wrc, accR[1]);
    accR[2] = fmaf(x2, wrc, accR[2]);
    accR[3] = fmaf(x3, wrc, accR[3]);
  }
#pragma unroll
  for (int rr = 0; rr < 4; ++rr)
    __builtin_nontemporal_store(accL[rr] + accR[rr] + bias,
                                &out[((size_t)(n0 + (w << 2) + rr) << 6) + lane]);
}

// ---------------------------------------------------------------------------
extern "C" void kernel_launch(void* const* d_in, const int* in_sizes, int n_in,
                              void* d_out, int out_size, void* d_ws, size_t ws_size,
                              hipStream_t stream) {
  const float* x  = (const float*)d_in[0];   // (8,64,32,32)
  const float* Wl = (const float*)d_in[1];   // (64,64)
  const float* bl = (const float*)d_in[2];   // (64,)
  const float* Wr = (const float*)d_in[3];   // (64,64)
  float* out = (float*)d_out;                // (8192,64)
  (void)d_ws; (void)ws_size;                 // workspace unused

  k_all<<<dim3(512), 256, 0, stream>>>(x, Wl, bl, Wr, out);
}

// Round 16
// 105.053 us; speedup vs baseline: 1.3888x; 1.3888x over previous
//
#include <hip/hip_runtime.h>
#include <cstdint>
#include <cstddef>

// Problem: B=8, C=64, H=W=32 -> N=8192 nodes, K=9 neighbors, OUT=64.
// Batches: b = [1024b,1024(b+1)) for b<=6, batch 7 = [7168,8190], batch 8 = {8191}.
// Node g <-> (b = g>>10, hw = g&1023); features x[b][c][hw] (node 8191 -> b=7).
//
// R22 == R20 revert (best measured: k_all 54.0us, total 105.7us).
//  R21's code-size compaction regressed 54->96us (LDS key-bridge + row
//  serialization + 2 barriers; VALUBusy 40->22%) -> I$ theory falsified.
//  Session summary: five structures (R13/16/17/18/20/21) bracket a ~54us
//  attractor; pipes underloaded; serial dependent chains at 2 waves/SIMD
//  dominate and every added-occupancy path doubles B traffic. R20 = R17
//  geometry (512 blocks x 16 rows, 4 rows/wave, B from global/L2, LDS = A +
//  W overlay) + DPP min-reduce tournament (VALU pipe, ~2-4cyc/level vs
//  ds_bpermute ~40+).
//  Exactness: ascending-ch fmaf chains for dot and sq on identical staged
//  bits -> d(n,n)==0 exactly; keys (orderable-dist<<32)|jj, jj=256q+4*lane+e
//  -> unique, lax.top_k smaller-index tie-break; batch-7 rows exclude
//  jj=1023; node 8191 singleton (mean = self).

typedef unsigned long long u64;

__global__ __launch_bounds__(256, 2) void k_all(const float* __restrict__ x,
                                                const float* __restrict__ Wl,
                                                const float* __restrict__ bl,
                                                const float* __restrict__ Wr,
                                                float* __restrict__ out) {
  // SH: A as float4[64ch][4grp] (4KB) until select done; then W overlay
  // WsL [64][65] @0, WsR @4160 (8320 floats).
  __shared__ float SH[8320];
  float4* Asf4 = (float4*)SH;

  int bi = (int)blockIdx.x, t = threadIdx.x;
  int lane = t & 63, w = t >> 6;
  int n0 = bi << 4;                  // 16 rows/block; batch bounds 16-aligned
  int s = (n0 >= 7168) ? 7168 : (n0 & ~1023);
  const float* xb = x + ((size_t)(s >> 10) << 16);       // batch plane base
  const float* xrow = x + ((size_t)(n0 >> 10) << 16) + (n0 & 1023);

  // stage A: ch = t>>2, grp g = t&3 -> rows n0+4g..n0+4g+3 of channel ch
  {
    int ch = t >> 2, g = t & 3;
    Asf4[t] = *(const float4*)&xrow[((size_t)ch << 10) + (g << 2)];
  }
  __syncthreads();

  // own-rows feature (ch=lane) for transform + singleton; read before overlay
  float4 av = Asf4[(lane << 2) + w];

  float acc[4][16];                  // rows 4w..4w+3 x lane's 16 cols
  float sqa[16];                     // lane's 16 col sq (ascending-ch chain)
#pragma unroll
  for (int r = 0; r < 4; ++r)
#pragma unroll
    for (int j = 0; j < 16; ++j) acc[r][j] = 0.f;
#pragma unroll
  for (int j = 0; j < 16; ++j) sqa[j] = 0.f;

  const float* xl = xb + (lane << 2);
#pragma unroll 4
  for (int ch = 0; ch < 64; ++ch) {
    float4 a4 = Asf4[(ch << 2) + w];                     // broadcast b128
    const float* xc = xl + ((size_t)ch << 10);
    float4 b0 = *(const float4*)&xc[0];                  // cols 4*lane..+3
    float4 b1 = *(const float4*)&xc[256];                // 256+4*lane..
    float4 b2 = *(const float4*)&xc[512];
    float4 b3 = *(const float4*)&xc[768];
    float bv[16] = {b0.x, b0.y, b0.z, b0.w, b1.x, b1.y, b1.z, b1.w,
                    b2.x, b2.y, b2.z, b2.w, b3.x, b3.y, b3.z, b3.w};
    float ar[4] = {a4.x, a4.y, a4.z, a4.w};
#pragma unroll
    for (int j = 0; j < 16; ++j) {
      sqa[j] = fmaf(bv[j], bv[j], sqa[j]);
      acc[0][j] = fmaf(ar[0], bv[j], acc[0][j]);
      acc[1][j] = fmaf(ar[1], bv[j], acc[1][j]);
      acc[2][j] = fmaf(ar[2], bv[j], acc[2][j]);
      acc[3][j] = fmaf(ar[3], bv[j], acc[3][j]);
    }
  }

  // 64-bit wave-min via DPP (VALU pipe): after the 6 levels the global min
  // is in lane 63; readlane broadcasts. Idempotent-min network:
  // xor1, xor2, half_mirror(8), mirror(16), bcast15(->32), bcast31(->64).
#define DPPMIN(CTRL)                                                         \
  {                                                                          \
    unsigned oh_ = (unsigned)__builtin_amdgcn_update_dpp(                    \
        (int)gh, (int)gh, CTRL, 0xF, 0xF, false);                            \
    unsigned ol_ = (unsigned)__builtin_amdgcn_update_dpp(                    \
        (int)gl, (int)gl, CTRL, 0xF, 0xF, false);                            \
    u64 cur_ = ((u64)gh << 32) | gl;                                         \
    u64 oth_ = ((u64)oh_ << 32) | ol_;                                       \
    bool take_ = oth_ < cur_;                                                \
    gh = take_ ? oh_ : gh;                                                   \
    gl = take_ ? ol_ : gl;                                                   \
  }

  // select per row: keys from registers. jj = 256q + 4*lane + e (R16 layout).
  float msum[4];
  int cnt[4];
#pragma unroll 4
  for (int rr = 0; rr < 4; ++rr) {
    int n = n0 + (w << 2) + rr;
    float xself = (rr == 0) ? av.x : (rr == 1) ? av.y : (rr == 2) ? av.z : av.w;
    if (n == 8191) {                 // singleton batch: self only
      msum[rr] = xself;
      cnt[rr] = 1;
    } else {
      cnt[rr] = 9;
      int ln = n - s;                // self col, local
      // si = sqa[slot_o] on owner lane; static cndmask select (rule #20)
      int slot_o = ((ln >> 8) << 2) | (ln & 3);
      float sv = sqa[0];
#pragma unroll
      for (int j = 1; j < 16; ++j) sv = (slot_o == j) ? sqa[j] : sv;
      float si = __int_as_float(
          __builtin_amdgcn_readlane(__float_as_int(sv), (ln & 255) >> 2));
      bool mlast = (n >= 7168);      // batch-7 rows exclude jj=1023 (node 8191)
      unsigned long long cand[16];
#pragma unroll
      for (int q = 0; q < 4; ++q) {
#pragma unroll
        for (int e = 0; e < 4; ++e) {
          float d = (si + sqa[(q << 2) + e]) - 2.f * acc[rr][(q << 2) + e];
          unsigned u = __float_as_uint(d);
          u = (u & 0x80000000u) ? ~u : (u | 0x80000000u);
          unsigned jj = (unsigned)((q << 8) + (lane << 2) + e);
          cand[(q << 2) + e] = ((unsigned long long)u << 32) | jj;
        }
      }
      if (mlast && lane == 63) cand[15] = ~0ull;  // jj=1023 -> q=3,lane=63,e=3
      // per-lane top-2 cache
      unsigned long long m1 = cand[0], m2 = cand[1];
      if (m2 < m1) { unsigned long long tt = m1; m1 = m2; m2 = tt; }
#pragma unroll
      for (int q = 2; q < 16; ++q) {
        unsigned long long c = cand[q];
        unsigned long long lo = (c < m1) ? c : m1;
        unsigned long long hi = (c < m1) ? m1 : c;
        m2 = (hi < m2) ? hi : m2;
        m1 = lo;
      }
      unsigned long long lm = m1;
      unsigned rmask = 0;
      bool stale = false;
      unsigned jloc[9];
#pragma unroll
      for (int kk = 0; kk < 9; ++kk) {
        unsigned gh = (unsigned)(lm >> 32), gl = (unsigned)lm;
        DPPMIN(0xB1)                 // quad_perm [1,0,3,2]  : xor1
        DPPMIN(0x4E)                 // quad_perm [2,3,0,1]  : xor2
        DPPMIN(0x141)                // row_half_mirror      : min-of-8
        DPPMIN(0x140)                // row_mirror           : min-of-16
        DPPMIN(0x142)                // row_bcast15          : min-of-32
        DPPMIN(0x143)                // row_bcast31          : min-of-64 @ lane63
        unsigned wh = __builtin_amdgcn_readlane((int)gh, 63);
        unsigned wl = __builtin_amdgcn_readlane((int)gl, 63);
        u64 g = ((u64)wh << 32) | wl;
        jloc[kk] = (unsigned)g & 1023u;
        if (lm == g) {               // exactly one winner lane (unique keys)
          unsigned slot = (((unsigned)g >> 6) & 12u) | ((unsigned)g & 3u);
          rmask |= 1u << slot;
          if (!stale) { lm = m2; stale = true; }
          else {                     // rare: rescan excluding removed slots
            unsigned long long best = ~0ull;
#pragma unroll
            for (int q = 0; q < 16; ++q) {
              bool alive = ((rmask >> q) & 1u) == 0u;
              unsigned long long c = cand[q];
              best = (alive && c < best) ? c : best;
            }
            lm = best;
          }
        }
      }
      // 9 independent gathers (wave-uniform jj; lane = channel), tree sum
      const float* gx = xb + ((size_t)lane << 10);
      float g0 = gx[jloc[0]], g1 = gx[jloc[1]], g2 = gx[jloc[2]];
      float g3 = gx[jloc[3]], g4 = gx[jloc[4]], g5 = gx[jloc[5]];
      float g6 = gx[jloc[6]], g7 = gx[jloc[7]], g8 = gx[jloc[8]];
      msum[rr] = (((g0 + g1) + (g2 + g3)) + ((g4 + g5) + (g6 + g7))) + g8;
    }
  }
  __syncthreads();                   // all A reads done before W overlay

  // stage Ws over dead A: WsL [64][65] @0, WsR @4160 (2 lanes/bank on read)
#pragma unroll
  for (int i = 0; i < 16; ++i) {
    int lin = t + (i << 8);
    int o = lin >> 6, c = lin & 63;
    SH[o * 65 + c] = Wl[lin];
    SH[4160 + o * 65 + c] = Wr[lin];
  }
  __syncthreads();

  // transform: lane = output channel; mean-then-linear (= reference order)
  float bias = bl[lane];
  float ms[4];
#pragma unroll
  for (int rr = 0; rr < 4; ++rr)
    ms[rr] = (cnt[rr] == 9) ? msum[rr] * (1.f / 9.f) : msum[rr];
  float xr[4] = {av.x, av.y, av.z, av.w};
  float accL[4] = {0.f, 0.f, 0.f, 0.f};
  float accR[4] = {0.f, 0.f, 0.f, 0.f};
#pragma unroll
  for (int c = 0; c < 64; ++c) {
    float wlc = SH[lane * 65 + c];
    float wrc = SH[4160 + lane * 65 + c];
#pragma unroll
    for (int rr = 0; rr < 4; ++rr) {
      float mc = __int_as_float(__builtin_amdgcn_readlane(__float_as_int(ms[rr]), c));
      float xc = __int_as_float(__builtin_amdgcn_readlane(__float_as_int(xr[rr]), c));
      accL[rr] = fmaf(mc, wlc, accL[rr]);
      accR[rr] = fmaf(xc, wrc, accR[rr]);
    }
  }
#pragma unroll
  for (int rr = 0; rr < 4; ++rr)
    __builtin_nontemporal_store(accL[rr] + accR[rr] + bias,
                                &out[((size_t)(n0 + (w << 2) + rr) << 6) + lane]);
}

// ---------------------------------------------------------------------------
extern "C" void kernel_launch(void* const* d_in, const int* in_sizes, int n_in,
                              void* d_out, int out_size, void* d_ws, size_t ws_size,
                              hipStream_t stream) {
  const float* x  = (const float*)d_in[0];   // (8,64,32,32)
  const float* Wl = (const float*)d_in[1];   // (64,64)
  const float* bl = (const float*)d_in[2];   // (64,)
  const float* Wr = (const float*)d_in[3];   // (64,64)
  float* out = (float*)d_out;                // (8192,64)
  (void)d_ws; (void)ws_size;                 // workspace unused

  k_all<<<dim3(512), 256, 0, stream>>>(x, Wl, bl, Wr, out);
}